// Round 10
// baseline (221.550 us; speedup 1.0000x reference)
//
#include <hip/hip_runtime.h>
#include <hip/hip_fp16.h>
#include <cmath>

#define NRAYS 4096
#define NSAMP 256

// Workspace layout (byte offsets):
//   dpt fp8  [i][y][x][16]   3*65536*16 = 3145728  (16B texels)
//   dlt fp16 [i][l][16]      3*256*32   = 24576
//   apt fp8  [i][y][x][32]   3*65536*32 = 6291456  (32B texels, ch24..31 pad)
//   alt fp8  [i][l][32]      3*256*32   = 24576
//   rayd [ray] 2xfloat4      = 131072
static constexpr size_t DPT_B = 0;
static constexpr size_t DLT_B = 3145728;
static constexpr size_t APT_B = DLT_B + 24576;     // 3170304
static constexpr size_t ALT_B = APT_B + 6291456;   // 9461760
static constexpr size_t RAY_B = ALT_B + 24576;     // 9486336
static constexpr size_t WS_NEED = RAY_B + 131072;  // 9617408 (~9.2 MiB)

typedef _Float16 __attribute__((ext_vector_type(2))) v2h;
typedef __attribute__((ext_vector_type(2))) float f32x2;

#if defined(__has_builtin)
#if __has_builtin(__builtin_amdgcn_cvt_scalef32_pk_f16_fp8)
#define HAS_SCVT 1
#endif
#endif
#ifndef HAS_SCVT
#define HAS_SCVT 0
#endif

__device__ __forceinline__ float dot2acc(__half2 a, __half2 b, float c) {
  return __builtin_amdgcn_fdot2(__builtin_bit_cast(v2h, a),
                                __builtin_bit_cast(v2h, b), c, false);
}

__device__ __forceinline__ __half2 lerp2(__half2 a, __half2 b, __half2 w) {
  return __hfma2(w, __hsub2(b, a), a);
}

// 16B load -> 4x half2
__device__ __forceinline__ void ld8h(const __half* p, __half2 h[4]) {
  uint4 r = *(const uint4*)p;
  h[0] = __builtin_bit_cast(__half2, r.x);
  h[1] = __builtin_bit_cast(__half2, r.y);
  h[2] = __builtin_bit_cast(__half2, r.z);
  h[3] = __builtin_bit_cast(__half2, r.w);
}

__device__ __forceinline__ unsigned pack2h(float a, float b) {
  return __builtin_bit_cast(unsigned, __floats2half2_rn(a, b));
}

// dword of 4 fp8(e4m3) -> 2x half2. gfx950 direct fp8->f16 (1 inst per half2)
// when available; else HW fp8->f32 cvt + pack.
__device__ __forceinline__ void dec4f8h(unsigned w, __half2& h0, __half2& h1) {
#if HAS_SCVT
  v2h a = __builtin_amdgcn_cvt_scalef32_pk_f16_fp8((int)w, 1.0f, false);
  v2h b = __builtin_amdgcn_cvt_scalef32_pk_f16_fp8((int)w, 1.0f, true);
  h0 = __builtin_bit_cast(__half2, a);
  h1 = __builtin_bit_cast(__half2, b);
#else
  f32x2 lo = __builtin_amdgcn_cvt_pk_f32_fp8((int)w, false);
  f32x2 hi = __builtin_amdgcn_cvt_pk_f32_fp8((int)w, true);
  h0 = __floats2half2_rn(lo.x, lo.y);
  h1 = __floats2half2_rn(hi.x, hi.y);
#endif
}

__device__ __forceinline__ void dec8f8(uint2 q, __half2 h[4]) {
  dec4f8h(q.x, h[0], h[1]);
  dec4f8h(q.y, h[2], h[3]);
}

__device__ __forceinline__ void dec16f8(uint4 q, __half2 h[8]) {
  dec4f8h(q.x, h[0], h[1]);
  dec4f8h(q.y, h[2], h[3]);
  dec4f8h(q.z, h[4], h[5]);
  dec4f8h(q.w, h[6], h[7]);
}

// 4 floats -> dword of 4 fp8(e4m3)
__device__ __forceinline__ unsigned pk4f8(float a, float b, float c, float d) {
  int w = __builtin_amdgcn_cvt_pk_fp8_f32(a, b, 0, false);
  w = __builtin_amdgcn_cvt_pk_fp8_f32(c, d, w, true);
  return (unsigned)w;
}

// align_corners=True grid coord -> (i0, frac). N=256 fixed.
__device__ __forceinline__ void grid_uv(float c, int& i0, float& w) {
  float f = (c + 1.0f) * 127.5f;
  float fl = floorf(f);
  fl = fminf(fmaxf(fl, 0.0f), 254.0f);
  i0 = (int)fl;
  w = f - fl;
}

__device__ __forceinline__ void bilin_w(float wx, float wy, __half2& W00,
                                        __half2& W01, __half2& W10, __half2& W11) {
  float ix = 1.0f - wx, iy = 1.0f - wy;
  W00 = __float2half2_rn(ix * iy);
  W01 = __float2half2_rn(wx * iy);
  W10 = __float2half2_rn(ix * wy);
  W11 = __float2half2_rn(wx * wy);
}

// ---------------------------------------------------------------------------
// Prep kernel: texture transpose+quantize AND per-ray precompute.
// No LDS: each thread reads its texel's channels directly (reads coalesce
// across the wave per channel) and writes one packed texel.
// blocks [0,768): density planes fp8 16B; [768,1536): app planes fp8 32B;
// 1536-1538 density lines fp16; 1539-1541 app lines fp8; [1542,1558): rays.
// ---------------------------------------------------------------------------
__global__ __launch_bounds__(256) void prep_kernel(
    const float* __restrict__ dp, const float* __restrict__ ap,
    const float* __restrict__ dl, const float* __restrict__ al,
    const float* __restrict__ rays, const float* __restrict__ aabb,
    unsigned char* __restrict__ dpt, unsigned char* __restrict__ apt,
    __half* __restrict__ dlt, unsigned char* __restrict__ alt,
    float4* __restrict__ rd) {
  int b = blockIdx.x, x = threadIdx.x;
  if (b < 768) {
    int i = b >> 8, y = b & 255;
    const float* src = dp + (size_t)(i * 16) * 65536 + y * 256 + x;
    float f[16];
#pragma unroll
    for (int c = 0; c < 16; ++c) f[c] = src[c * 65536];
    uint4 v;
    v.x = pk4f8(f[0], f[1], f[2], f[3]);
    v.y = pk4f8(f[4], f[5], f[6], f[7]);
    v.z = pk4f8(f[8], f[9], f[10], f[11]);
    v.w = pk4f8(f[12], f[13], f[14], f[15]);
    *(uint4*)(dpt + ((size_t)(i << 16) + (y << 8) + x) * 16) = v;
  } else if (b < 1536) {
    int t = b - 768;
    int i = t >> 8, y = t & 255;
    const float* src = ap + (size_t)(i * 24) * 65536 + y * 256 + x;
    float f[24];
#pragma unroll
    for (int c = 0; c < 24; ++c) f[c] = src[c * 65536];
    uint4 v0, v1;
    v0.x = pk4f8(f[0], f[1], f[2], f[3]);
    v0.y = pk4f8(f[4], f[5], f[6], f[7]);
    v0.z = pk4f8(f[8], f[9], f[10], f[11]);
    v0.w = pk4f8(f[12], f[13], f[14], f[15]);
    v1.x = pk4f8(f[16], f[17], f[18], f[19]);
    v1.y = pk4f8(f[20], f[21], f[22], f[23]);
    v1.z = 0u; v1.w = 0u;
    uint4* dst = (uint4*)(apt + ((size_t)(i << 16) + (y << 8) + x) * 32);
    dst[0] = v0; dst[1] = v1;
  } else if (b < 1539) {
    int i = b - 1536, l = x;
    float f[16];
#pragma unroll
    for (int c = 0; c < 16; ++c) f[c] = dl[(i * 16 + c) * 256 + l];
    uint4 v0, v1;
    v0.x = pack2h(f[0], f[1]);   v0.y = pack2h(f[2], f[3]);
    v0.z = pack2h(f[4], f[5]);   v0.w = pack2h(f[6], f[7]);
    v1.x = pack2h(f[8], f[9]);   v1.y = pack2h(f[10], f[11]);
    v1.z = pack2h(f[12], f[13]); v1.w = pack2h(f[14], f[15]);
    uint4* dst = (uint4*)(dlt + (i * 256 + l) * 16);
    dst[0] = v0; dst[1] = v1;
  } else if (b < 1542) {
    int i = b - 1539, l = x;
    float f[24];
#pragma unroll
    for (int c = 0; c < 24; ++c) f[c] = al[(i * 24 + c) * 256 + l];
    uint4 v0, v1;
    v0.x = pk4f8(f[0], f[1], f[2], f[3]);
    v0.y = pk4f8(f[4], f[5], f[6], f[7]);
    v0.z = pk4f8(f[8], f[9], f[10], f[11]);
    v0.w = pk4f8(f[12], f[13], f[14], f[15]);
    v1.x = pk4f8(f[16], f[17], f[18], f[19]);
    v1.y = pk4f8(f[20], f[21], f[22], f[23]);
    v1.z = 0u; v1.w = 0u;
    uint4* dst = (uint4*)(alt + (i * 256 + l) * 32);
    dst[0] = v0; dst[1] = v1;
  } else {
    int r = (b - 1542) * 256 + x;
    if (r < NRAYS) {
      float o0 = rays[r * 6 + 0], o1 = rays[r * 6 + 1], o2 = rays[r * 6 + 2];
      float d0 = rays[r * 6 + 3], d1 = rays[r * 6 + 4], d2 = rays[r * 6 + 5];
      float A0 = aabb[0], A1 = aabb[1], A2 = aabb[2];
      float B0 = aabb[3], B1 = aabb[4], B2 = aabb[5];
      float v0 = fabsf(d0) < 1e-6f ? 1e-6f : d0;
      float v1 = fabsf(d1) < 1e-6f ? 1e-6f : d1;
      float v2 = fabsf(d2) < 1e-6f ? 1e-6f : d2;
      float ra0 = (B0 - o0) / v0, rb0 = (A0 - o0) / v0;
      float ra1 = (B1 - o1) / v1, rb1 = (A1 - o1) / v1;
      float ra2 = (B2 - o2) / v2, rb2 = (A2 - o2) / v2;
      float tmin = fmaxf(fmaxf(fminf(ra0, rb0), fminf(ra1, rb1)), fminf(ra2, rb2));
      tmin = fmaxf(tmin, 0.05f);
      float tmax = fminf(fminf(fmaxf(ra0, rb0), fmaxf(ra1, rb1)), fmaxf(ra2, rb2));
      tmax = fmaxf(tmax, tmin + 0.001f);
      float dt = (tmax - tmin) * (1.0f / 255.0f);
      float s0 = 2.0f / (B0 - A0), s1 = 2.0f / (B1 - A1), s2 = 2.0f / (B2 - A2);
      float4 a2, b2;
      a2.x = (o0 - A0) * s0 - 1.0f; a2.y = (o1 - A1) * s1 - 1.0f;
      a2.z = (o2 - A2) * s2 - 1.0f; a2.w = tmin;
      b2.x = d0 * s0; b2.y = d1 * s1; b2.z = d2 * s2; b2.w = dt;
      rd[r * 2] = a2;
      rd[r * 2 + 1] = b2;
    }
  }
}

// ---------------------------------------------------------------------------
// density mode (fp8 plane, fp16 line): lane sub owns 8 channels. 8B loads.
// ---------------------------------------------------------------------------
__device__ __forceinline__ float density_f8(const unsigned char* __restrict__ pl,
                                            const __half* __restrict__ ln,
                                            int x0, int y0, int l0,
                                            __half2 W00, __half2 W01,
                                            __half2 W10, __half2 W11,
                                            __half2 wl, int sub, float acc) {
  const unsigned char* p = pl + (size_t)((y0 * 256 + x0) << 4) + sub * 8;
  uint2 q00 = *(const uint2*)p;
  uint2 q01 = *(const uint2*)(p + 16);
  uint2 q10 = *(const uint2*)(p + 4096);
  uint2 q11 = *(const uint2*)(p + 4096 + 16);
  __half2 A[4], B[4], C[4], D[4], la[4], lb[4];
  dec8f8(q00, A); dec8f8(q01, B); dec8f8(q10, C); dec8f8(q11, D);
  const __half* lp = ln + (l0 << 4) + sub * 8;
  ld8h(lp, la); ld8h(lp + 16, lb);
#pragma unroll
  for (int r = 0; r < 4; ++r) {
    __half2 m = __hmul2(W00, A[r]);
    m = __hfma2(W01, B[r], m);
    m = __hfma2(W10, C[r], m);
    m = __hfma2(W11, D[r], m);
    __half2 l = lerp2(la[r], lb[r], wl);
    acc = dot2acc(m, l, acc);
  }
  return acc;
}

// ---------------------------------------------------------------------------
// app mode (fp8, 32B aligned texels): lane sub owns 16 padded channels.
// One uint4 load per corner.
// ---------------------------------------------------------------------------
__device__ __forceinline__ void app_f8(const unsigned char* __restrict__ pl,
                                       const unsigned char* __restrict__ ln,
                                       const __half2* __restrict__ btR,
                                       const __half2* __restrict__ btG,
                                       const __half2* __restrict__ btB,
                                       int x0, int y0, int l0,
                                       __half2 W00, __half2 W01,
                                       __half2 W10, __half2 W11,
                                       __half2 wl, int sub,
                                       float& dr, float& dg, float& db) {
  const unsigned char* p = pl + ((size_t)(y0 * 256 + x0) << 5) + sub * 16;
  uint4 qA = *(const uint4*)p;
  uint4 qB = *(const uint4*)(p + 32);
  uint4 qC = *(const uint4*)(p + 8192);
  uint4 qD = *(const uint4*)(p + 8192 + 32);
  const unsigned char* lp = ln + (l0 << 5) + sub * 16;
  uint4 qLA = *(const uint4*)lp;
  uint4 qLB = *(const uint4*)(lp + 32);
  __half2 A[8], B[8], C[8], D[8], LA[8], LB[8];
  dec16f8(qA, A); dec16f8(qB, B); dec16f8(qC, C); dec16f8(qD, D);
  dec16f8(qLA, LA); dec16f8(qLB, LB);
#pragma unroll
  for (int r = 0; r < 8; ++r) {
    __half2 m = __hmul2(W00, A[r]);
    m = __hfma2(W01, B[r], m);
    m = __hfma2(W10, C[r], m);
    m = __hfma2(W11, D[r], m);
    __half2 l = lerp2(LA[r], LB[r], wl);
    __half2 av = __hmul2(m, l);
    dr = dot2acc(av, btR[r], dr);
    dg = dot2acc(av, btG[r], dg);
    db = dot2acc(av, btB[r], db);
  }
}

// ---------------------------------------------------------------------------
// Fused render: block = 512 threads = 1 ray (256 samples x 2 lanes).
// Sample phase -> 4KB LDS (fp32) -> one barrier -> wave 0 scans+writes.
// ---------------------------------------------------------------------------
__global__ __launch_bounds__(512, 8) void render_fused(
    const float4* __restrict__ rd, const float* __restrict__ basis,
    const unsigned char* __restrict__ dpt, const __half* __restrict__ dlt,
    const unsigned char* __restrict__ apt, const unsigned char* __restrict__ alt,
    float* __restrict__ out) {
  __shared__ __align__(16) __half bth[3][3][32];  // [k][mode][ch], pad zeroed
  __shared__ __align__(16) float4 sm[NSAMP];      // alpha, r, g, b
  int tid = threadIdx.x;
  if (tid < 288) {  // 288 <= 512: single pass
    int k = tid / 96, rem = tid - k * 96;
    int m = rem >> 5, c = rem & 31;
    float v = (c < 24) ? basis[(m * 24 + c) * 3 + k] : 0.0f;
    bth[k][m][c] = __float2half(v);
  }

  int ray = blockIdx.x;
  int j = tid >> 1, sub = tid & 1;

  float4 ra = rd[ray * 2];
  float4 rb = rd[ray * 2 + 1];
  float z = fmaf((float)j, rb.w, ra.w);
  float c0 = fmaf(rb.x, z, ra.x);
  float c1 = fmaf(rb.y, z, ra.y);
  float c2 = fmaf(rb.z, z, ra.z);
  bool inside = (fabsf(c0) <= 1.0f) && (fabsf(c1) <= 1.0f) && (fabsf(c2) <= 1.0f);

  __syncthreads();  // bth ready

  float sig = 0.f, dr = 0.f, dg = 0.f, db = 0.f;
  if (inside) {
    int i0, i1, i2;
    float w0, w1, w2;
    grid_uv(c0, i0, w0);
    grid_uv(c1, i1, w1);
    grid_uv(c2, i2, w2);
    __half2 h0 = __float2half2_rn(w0);
    __half2 h1 = __float2half2_rn(w1);
    __half2 h2 = __float2half2_rn(w2);
    // MAT_MODE = [(0,1),(0,2),(1,2)], VEC_MODE = [2,1,0]
    __half2 Wa00, Wa01, Wa10, Wa11;  // mode 0: (w0,w1)
    __half2 Wb00, Wb01, Wb10, Wb11;  // mode 1: (w0,w2)
    __half2 Wc00, Wc01, Wc10, Wc11;  // mode 2: (w1,w2)
    bilin_w(w0, w1, Wa00, Wa01, Wa10, Wa11);
    bilin_w(w0, w2, Wb00, Wb01, Wb10, Wb11);
    bilin_w(w1, w2, Wc00, Wc01, Wc10, Wc11);

    sig = density_f8(dpt + 0 * 1048576, dlt + 0 * 4096, i0, i1, i2,
                     Wa00, Wa01, Wa10, Wa11, h2, sub, sig);
    sig = density_f8(dpt + 1 * 1048576, dlt + 1 * 4096, i0, i2, i1,
                     Wb00, Wb01, Wb10, Wb11, h1, sub, sig);
    sig = density_f8(dpt + 2 * 1048576, dlt + 2 * 4096, i1, i2, i0,
                     Wc00, Wc01, Wc10, Wc11, h0, sub, sig);
    app_f8(apt + 0 * 2097152, alt + 0 * 8192,
           (const __half2*)&bth[0][0][sub * 16], (const __half2*)&bth[1][0][sub * 16],
           (const __half2*)&bth[2][0][sub * 16], i0, i1, i2,
           Wa00, Wa01, Wa10, Wa11, h2, sub, dr, dg, db);
    app_f8(apt + 1 * 2097152, alt + 1 * 8192,
           (const __half2*)&bth[0][1][sub * 16], (const __half2*)&bth[1][1][sub * 16],
           (const __half2*)&bth[2][1][sub * 16], i0, i2, i1,
           Wb00, Wb01, Wb10, Wb11, h1, sub, dr, dg, db);
    app_f8(apt + 2 * 2097152, alt + 2 * 8192,
           (const __half2*)&bth[0][2][sub * 16], (const __half2*)&bth[1][2][sub * 16],
           (const __half2*)&bth[2][2][sub * 16], i1, i2, i0,
           Wc00, Wc01, Wc10, Wc11, h0, sub, dr, dg, db);
  }
  // reduce over the 2-lane group
  sig += __shfl_xor(sig, 1, 64);
  dr += __shfl_xor(dr, 1, 64);
  dg += __shfl_xor(dg, 1, 64);
  db += __shfl_xor(db, 1, 64);

  if (sub == 0) {
    // softplus via fast log/exp: sp = max(x,0) + log(1 + exp(-|x|))
    float e = __expf(-fabsf(sig));
    float sp = fmaxf(sig, 0.f) + __logf(1.0f + e);
    float4 sv;
    sv.x = inside ? (1.0f - __expf(-sp * rb.w)) : 0.0f;
    sv.y = __builtin_amdgcn_rcpf(1.0f + __expf(-dr));
    sv.z = __builtin_amdgcn_rcpf(1.0f + __expf(-dg));
    sv.w = __builtin_amdgcn_rcpf(1.0f + __expf(-db));
    sm[j] = sv;
  }
  __syncthreads();

  // wave 0: transmittance scan + composite
  if (tid < 64) {
    int lane = tid;
    float tmin = ra.w, dt = rb.w;
    float C = 1.0f;
    float racc = 0.f, gacc = 0.f, bacc = 0.f, wsum = 0.f, dsum = 0.f;
    for (int q = 0; q < 4; ++q) {
      int jj = q * 64 + lane;
      float4 sv = sm[jj];
      float alpha = sv.x;
      float zz = fmaf((float)jj, dt, tmin);
      float p = 1.0f - alpha + 1e-10f;
#pragma unroll
      for (int off = 1; off < 64; off <<= 1) {
        float t = __shfl_up(p, off, 64);
        if (lane >= off) p *= t;
      }
      float tot = __shfl(p, 63, 64);
      float e = __shfl_up(p, 1, 64);
      if (lane == 0) e = 1.0f;
      float Tj = C * e;
      float w = alpha * Tj;
      racc += w * sv.y;
      gacc += w * sv.z;
      bacc += w * sv.w;
      wsum += w;
      dsum += w * zz;
      C *= tot;
    }
#pragma unroll
    for (int off = 32; off > 0; off >>= 1) {
      racc += __shfl_down(racc, off, 64);
      gacc += __shfl_down(gacc, off, 64);
      bacc += __shfl_down(bacc, off, 64);
      wsum += __shfl_down(wsum, off, 64);
      dsum += __shfl_down(dsum, off, 64);
    }
    if (lane == 0) {
      float bgw = 1.0f - wsum;  // WHITE_BG
      out[ray * 3 + 0] = fminf(fmaxf(racc + bgw, 0.f), 1.f);
      out[ray * 3 + 1] = fminf(fmaxf(gacc + bgw, 0.f), 1.f);
      out[ray * 3 + 2] = fminf(fmaxf(bacc + bgw, 0.f), 1.f);
      out[NRAYS * 3 + ray] = dsum;
    }
  }
}

// ---------------------------------------------------------------------------
// Fallback (ws too small): single-kernel fp32 render on original layout.
// ---------------------------------------------------------------------------
__device__ __forceinline__ float density_orig(const float* __restrict__ plane,
                                              const float* __restrict__ line,
                                              float cx, float cy, float cw) {
  int x0, y0, l0; float wx, wy, wl;
  grid_uv(cx, x0, wx); grid_uv(cy, y0, wy); grid_uv(cw, l0, wl);
  int base = y0 * 256 + x0;
  float s = 0.0f;
#pragma unroll 4
  for (int c = 0; c < 16; ++c) {
    const float* pc = plane + c * 65536;
    float v00 = pc[base], v01 = pc[base + 1];
    float v10 = pc[base + 256], v11 = pc[base + 257];
    float top = fmaf(wx, v01 - v00, v00);
    float bot = fmaf(wx, v11 - v10, v10);
    float mid = fmaf(wy, bot - top, top);
    float la = line[c * 256 + l0], lb = line[c * 256 + l0 + 1];
    float lv = fmaf(wl, lb - la, la);
    s += mid * lv;
  }
  return s;
}

__device__ __forceinline__ void app_orig(const float* __restrict__ plane,
                                         const float* __restrict__ line,
                                         const float* __restrict__ btR,
                                         const float* __restrict__ btG,
                                         const float* __restrict__ btB,
                                         float cx, float cy, float cw,
                                         float& dr, float& dg, float& db) {
  int x0, y0, l0; float wx, wy, wl;
  grid_uv(cx, x0, wx); grid_uv(cy, y0, wy); grid_uv(cw, l0, wl);
  int base = y0 * 256 + x0;
#pragma unroll 4
  for (int c = 0; c < 24; ++c) {
    const float* pc = plane + c * 65536;
    float v00 = pc[base], v01 = pc[base + 1];
    float v10 = pc[base + 256], v11 = pc[base + 257];
    float top = fmaf(wx, v01 - v00, v00);
    float bot = fmaf(wx, v11 - v10, v10);
    float mid = fmaf(wy, bot - top, top);
    float la = line[c * 256 + l0], lb = line[c * 256 + l0 + 1];
    float lv = fmaf(wl, lb - la, la);
    float av = mid * lv;
    dr += av * btR[c]; dg += av * btG[c]; db += av * btB[c];
  }
}

__global__ __launch_bounds__(256) void render_fallback(
    const float* __restrict__ rays, const float* __restrict__ basis,
    const float* __restrict__ aabb, const float* __restrict__ dplane,
    const float* __restrict__ dline, const float* __restrict__ aplane,
    const float* __restrict__ aline, float* __restrict__ out) {
  __shared__ float bt[3 * 72];
  int tid = threadIdx.x;
  if (tid < 216) {
    int k = tid / 72, r = tid - k * 72;
    bt[tid] = basis[r * 3 + k];
  }
  __syncthreads();
  int lane = tid & 63;
  int ray = blockIdx.x * 4 + (tid >> 6);

  float o0 = rays[ray * 6 + 0], o1 = rays[ray * 6 + 1], o2 = rays[ray * 6 + 2];
  float d0 = rays[ray * 6 + 3], d1 = rays[ray * 6 + 4], d2 = rays[ray * 6 + 5];
  float A0 = aabb[0], A1 = aabb[1], A2 = aabb[2];
  float B0 = aabb[3], B1 = aabb[4], B2 = aabb[5];
  float v0 = fabsf(d0) < 1e-6f ? 1e-6f : d0;
  float v1 = fabsf(d1) < 1e-6f ? 1e-6f : d1;
  float v2 = fabsf(d2) < 1e-6f ? 1e-6f : d2;
  float ra0 = (B0 - o0) / v0, rb0 = (A0 - o0) / v0;
  float ra1 = (B1 - o1) / v1, rb1 = (A1 - o1) / v1;
  float ra2 = (B2 - o2) / v2, rb2 = (A2 - o2) / v2;
  float tmin = fmaxf(fmaxf(fminf(ra0, rb0), fminf(ra1, rb1)), fminf(ra2, rb2));
  tmin = fmaxf(tmin, 0.05f);
  float tmax = fminf(fminf(fmaxf(ra0, rb0), fmaxf(ra1, rb1)), fmaxf(ra2, rb2));
  tmax = fmaxf(tmax, tmin + 0.001f);
  float dt = (tmax - tmin) * (1.0f / 255.0f);
  float s0 = 2.0f / (B0 - A0), s1 = 2.0f / (B1 - A1), s2 = 2.0f / (B2 - A2);

  float C = 1.0f;
  float racc = 0.f, gacc = 0.f, bacc = 0.f, wsum = 0.f, dsum = 0.f;
  for (int q = 0; q < 4; ++q) {
    int j = q * 64 + lane;
    float sfrac = (float)j * (1.0f / 255.0f);
    float z = tmin * (1.0f - sfrac) + tmax * sfrac;
    float c0 = (o0 + d0 * z - A0) * s0 - 1.0f;
    float c1 = (o1 + d1 * z - A1) * s1 - 1.0f;
    float c2 = (o2 + d2 * z - A2) * s2 - 1.0f;
    bool inside = (fabsf(c0) <= 1.0f) && (fabsf(c1) <= 1.0f) && (fabsf(c2) <= 1.0f);
    float alpha = 0.f, cr = 0.f, cg = 0.f, cb = 0.f;
    if (inside) {
      float sig = 0.f, dr = 0.f, dg = 0.f, db = 0.f;
      sig += density_orig(dplane + 0 * 1048576, dline + 0 * 4096, c0, c1, c2);
      sig += density_orig(dplane + 1 * 1048576, dline + 1 * 4096, c0, c2, c1);
      sig += density_orig(dplane + 2 * 1048576, dline + 2 * 4096, c1, c2, c0);
      app_orig(aplane + 0 * 1572864, aline + 0 * 6144,
               &bt[0 * 72 + 0], &bt[1 * 72 + 0], &bt[2 * 72 + 0],
               c0, c1, c2, dr, dg, db);
      app_orig(aplane + 1 * 1572864, aline + 1 * 6144,
               &bt[0 * 72 + 24], &bt[1 * 72 + 24], &bt[2 * 72 + 24],
               c0, c2, c1, dr, dg, db);
      app_orig(aplane + 2 * 1572864, aline + 2 * 6144,
               &bt[0 * 72 + 48], &bt[1 * 72 + 48], &bt[2 * 72 + 48],
               c1, c2, c0, dr, dg, db);
      float sp = fmaxf(sig, 0.f) + log1pf(expf(-fabsf(sig)));
      alpha = 1.0f - expf(-sp * dt);
      cr = 1.0f / (1.0f + expf(-dr));
      cg = 1.0f / (1.0f + expf(-dg));
      cb = 1.0f / (1.0f + expf(-db));
    }
    float p = 1.0f - alpha + 1e-10f;
#pragma unroll
    for (int off = 1; off < 64; off <<= 1) {
      float t = __shfl_up(p, off, 64);
      if (lane >= off) p *= t;
    }
    float tot = __shfl(p, 63, 64);
    float e = __shfl_up(p, 1, 64);
    if (lane == 0) e = 1.0f;
    float Tj = C * e;
    float w = alpha * Tj;
    racc += w * cr; gacc += w * cg; bacc += w * cb;
    wsum += w; dsum += w * z;
    C *= tot;
  }
#pragma unroll
  for (int off = 32; off > 0; off >>= 1) {
    racc += __shfl_down(racc, off, 64);
    gacc += __shfl_down(gacc, off, 64);
    bacc += __shfl_down(bacc, off, 64);
    wsum += __shfl_down(wsum, off, 64);
    dsum += __shfl_down(dsum, off, 64);
  }
  if (lane == 0) {
    float bgw = 1.0f - wsum;
    out[ray * 3 + 0] = fminf(fmaxf(racc + bgw, 0.f), 1.f);
    out[ray * 3 + 1] = fminf(fmaxf(gacc + bgw, 0.f), 1.f);
    out[ray * 3 + 2] = fminf(fmaxf(bacc + bgw, 0.f), 1.f);
    out[NRAYS * 3 + ray] = dsum;
  }
}

extern "C" void kernel_launch(void* const* d_in, const int* in_sizes, int n_in,
                              void* d_out, int out_size, void* d_ws, size_t ws_size,
                              hipStream_t stream) {
  const float* rays  = (const float*)d_in[0];
  const float* dp    = (const float*)d_in[1];
  const float* dl    = (const float*)d_in[2];
  const float* ap    = (const float*)d_in[3];
  const float* al    = (const float*)d_in[4];
  const float* basis = (const float*)d_in[5];
  const float* aabb  = (const float*)d_in[6];
  float* out = (float*)d_out;

  if (ws_size >= WS_NEED) {
    char* ws = (char*)d_ws;
    unsigned char* dpt = (unsigned char*)(ws + DPT_B);
    __half* dlt = (__half*)(ws + DLT_B);
    unsigned char* apt = (unsigned char*)(ws + APT_B);
    unsigned char* alt = (unsigned char*)(ws + ALT_B);
    float4* rayd = (float4*)(ws + RAY_B);
    prep_kernel<<<1558, 256, 0, stream>>>(dp, ap, dl, al, rays, aabb,
                                          dpt, apt, dlt, alt, rayd);
    render_fused<<<NRAYS, 512, 0, stream>>>(rayd, basis, dpt, dlt, apt, alt, out);
  } else {
    render_fallback<<<NRAYS / 4, 256, 0, stream>>>(
        rays, basis, aabb, dp, dl, ap, al, out);
  }
}

// Round 11
// 154.757 us; speedup vs baseline: 1.4316x; 1.4316x over previous
//
#include <hip/hip_runtime.h>
#include <hip/hip_fp16.h>
#include <cmath>

#define NRAYS 4096
#define NSAMP 256

// Workspace layout (byte offsets):
//   dpt fp8  [i][y][x][16]   3*65536*16 = 3145728  (16B texels)
//   dlt fp16 [i][l][16]      3*256*32   = 24576
//   apt fp8  [i][y][x][32]   3*65536*32 = 6291456  (32B texels, ch24..31 pad)
//   alt fp8  [i][l][32]      3*256*32   = 24576
//   rayd [ray] 2xfloat4      = 131072
static constexpr size_t DPT_B = 0;
static constexpr size_t DLT_B = 3145728;
static constexpr size_t APT_B = DLT_B + 24576;     // 3170304
static constexpr size_t ALT_B = APT_B + 6291456;   // 9461760
static constexpr size_t RAY_B = ALT_B + 24576;     // 9486336
static constexpr size_t WS_NEED = RAY_B + 131072;  // 9617408 (~9.2 MiB)

typedef _Float16 __attribute__((ext_vector_type(2))) v2h;
typedef __attribute__((ext_vector_type(2))) float f32x2;

#if defined(__has_builtin)
#if __has_builtin(__builtin_amdgcn_cvt_scalef32_pk_f16_fp8)
#define HAS_SCVT 1
#endif
#endif
#ifndef HAS_SCVT
#define HAS_SCVT 0
#endif

__device__ __forceinline__ float dot2acc(__half2 a, __half2 b, float c) {
  return __builtin_amdgcn_fdot2(__builtin_bit_cast(v2h, a),
                                __builtin_bit_cast(v2h, b), c, false);
}

__device__ __forceinline__ __half2 lerp2(__half2 a, __half2 b, __half2 w) {
  return __hfma2(w, __hsub2(b, a), a);
}

// 16B load -> 4x half2
__device__ __forceinline__ void ld8h(const __half* p, __half2 h[4]) {
  uint4 r = *(const uint4*)p;
  h[0] = __builtin_bit_cast(__half2, r.x);
  h[1] = __builtin_bit_cast(__half2, r.y);
  h[2] = __builtin_bit_cast(__half2, r.z);
  h[3] = __builtin_bit_cast(__half2, r.w);
}

__device__ __forceinline__ unsigned pack2h(float a, float b) {
  return __builtin_bit_cast(unsigned, __floats2half2_rn(a, b));
}

// dword of 4 fp8(e4m3) -> 2x half2. gfx950 direct fp8->f16 (1 inst per half2)
// when available; else HW fp8->f32 cvt + pack.
__device__ __forceinline__ void dec4f8h(unsigned w, __half2& h0, __half2& h1) {
#if HAS_SCVT
  v2h a = __builtin_amdgcn_cvt_scalef32_pk_f16_fp8((int)w, 1.0f, false);
  v2h b = __builtin_amdgcn_cvt_scalef32_pk_f16_fp8((int)w, 1.0f, true);
  h0 = __builtin_bit_cast(__half2, a);
  h1 = __builtin_bit_cast(__half2, b);
#else
  f32x2 lo = __builtin_amdgcn_cvt_pk_f32_fp8((int)w, false);
  f32x2 hi = __builtin_amdgcn_cvt_pk_f32_fp8((int)w, true);
  h0 = __floats2half2_rn(lo.x, lo.y);
  h1 = __floats2half2_rn(hi.x, hi.y);
#endif
}

__device__ __forceinline__ void dec8f8(uint2 q, __half2 h[4]) {
  dec4f8h(q.x, h[0], h[1]);
  dec4f8h(q.y, h[2], h[3]);
}

__device__ __forceinline__ void dec16f8(uint4 q, __half2 h[8]) {
  dec4f8h(q.x, h[0], h[1]);
  dec4f8h(q.y, h[2], h[3]);
  dec4f8h(q.z, h[4], h[5]);
  dec4f8h(q.w, h[6], h[7]);
}

// 4 floats -> dword of 4 fp8(e4m3)
__device__ __forceinline__ unsigned pk4f8(float a, float b, float c, float d) {
  int w = __builtin_amdgcn_cvt_pk_fp8_f32(a, b, 0, false);
  w = __builtin_amdgcn_cvt_pk_fp8_f32(c, d, w, true);
  return (unsigned)w;
}

// align_corners=True grid coord -> (i0, frac). N=256 fixed.
__device__ __forceinline__ void grid_uv(float c, int& i0, float& w) {
  float f = (c + 1.0f) * 127.5f;
  float fl = floorf(f);
  fl = fminf(fmaxf(fl, 0.0f), 254.0f);
  i0 = (int)fl;
  w = f - fl;
}

__device__ __forceinline__ void bilin_w(float wx, float wy, __half2& W00,
                                        __half2& W01, __half2& W10, __half2& W11) {
  float ix = 1.0f - wx, iy = 1.0f - wy;
  W00 = __float2half2_rn(ix * iy);
  W01 = __float2half2_rn(wx * iy);
  W10 = __float2half2_rn(ix * wy);
  W11 = __float2half2_rn(wx * wy);
}

// ---------------------------------------------------------------------------
// Prep kernel: texture transpose+quantize AND per-ray precompute.
// No LDS: each thread reads its texel's channels directly (reads coalesce
// across the wave per channel) and writes one packed texel.
// blocks [0,768): density planes fp8 16B; [768,1536): app planes fp8 32B;
// 1536-1538 density lines fp16; 1539-1541 app lines fp8; [1542,1558): rays.
// ---------------------------------------------------------------------------
__global__ __launch_bounds__(256) void prep_kernel(
    const float* __restrict__ dp, const float* __restrict__ ap,
    const float* __restrict__ dl, const float* __restrict__ al,
    const float* __restrict__ rays, const float* __restrict__ aabb,
    unsigned char* __restrict__ dpt, unsigned char* __restrict__ apt,
    __half* __restrict__ dlt, unsigned char* __restrict__ alt,
    float4* __restrict__ rd) {
  int b = blockIdx.x, x = threadIdx.x;
  if (b < 768) {
    int i = b >> 8, y = b & 255;
    const float* src = dp + (size_t)(i * 16) * 65536 + y * 256 + x;
    float f[16];
#pragma unroll
    for (int c = 0; c < 16; ++c) f[c] = src[c * 65536];
    uint4 v;
    v.x = pk4f8(f[0], f[1], f[2], f[3]);
    v.y = pk4f8(f[4], f[5], f[6], f[7]);
    v.z = pk4f8(f[8], f[9], f[10], f[11]);
    v.w = pk4f8(f[12], f[13], f[14], f[15]);
    *(uint4*)(dpt + ((size_t)(i << 16) + (y << 8) + x) * 16) = v;
  } else if (b < 1536) {
    int t = b - 768;
    int i = t >> 8, y = t & 255;
    const float* src = ap + (size_t)(i * 24) * 65536 + y * 256 + x;
    float f[24];
#pragma unroll
    for (int c = 0; c < 24; ++c) f[c] = src[c * 65536];
    uint4 v0, v1;
    v0.x = pk4f8(f[0], f[1], f[2], f[3]);
    v0.y = pk4f8(f[4], f[5], f[6], f[7]);
    v0.z = pk4f8(f[8], f[9], f[10], f[11]);
    v0.w = pk4f8(f[12], f[13], f[14], f[15]);
    v1.x = pk4f8(f[16], f[17], f[18], f[19]);
    v1.y = pk4f8(f[20], f[21], f[22], f[23]);
    v1.z = 0u; v1.w = 0u;
    uint4* dst = (uint4*)(apt + ((size_t)(i << 16) + (y << 8) + x) * 32);
    dst[0] = v0; dst[1] = v1;
  } else if (b < 1539) {
    int i = b - 1536, l = x;
    float f[16];
#pragma unroll
    for (int c = 0; c < 16; ++c) f[c] = dl[(i * 16 + c) * 256 + l];
    uint4 v0, v1;
    v0.x = pack2h(f[0], f[1]);   v0.y = pack2h(f[2], f[3]);
    v0.z = pack2h(f[4], f[5]);   v0.w = pack2h(f[6], f[7]);
    v1.x = pack2h(f[8], f[9]);   v1.y = pack2h(f[10], f[11]);
    v1.z = pack2h(f[12], f[13]); v1.w = pack2h(f[14], f[15]);
    uint4* dst = (uint4*)(dlt + (i * 256 + l) * 16);
    dst[0] = v0; dst[1] = v1;
  } else if (b < 1542) {
    int i = b - 1539, l = x;
    float f[24];
#pragma unroll
    for (int c = 0; c < 24; ++c) f[c] = al[(i * 24 + c) * 256 + l];
    uint4 v0, v1;
    v0.x = pk4f8(f[0], f[1], f[2], f[3]);
    v0.y = pk4f8(f[4], f[5], f[6], f[7]);
    v0.z = pk4f8(f[8], f[9], f[10], f[11]);
    v0.w = pk4f8(f[12], f[13], f[14], f[15]);
    v1.x = pk4f8(f[16], f[17], f[18], f[19]);
    v1.y = pk4f8(f[20], f[21], f[22], f[23]);
    v1.z = 0u; v1.w = 0u;
    uint4* dst = (uint4*)(alt + (i * 256 + l) * 32);
    dst[0] = v0; dst[1] = v1;
  } else {
    int r = (b - 1542) * 256 + x;
    if (r < NRAYS) {
      float o0 = rays[r * 6 + 0], o1 = rays[r * 6 + 1], o2 = rays[r * 6 + 2];
      float d0 = rays[r * 6 + 3], d1 = rays[r * 6 + 4], d2 = rays[r * 6 + 5];
      float A0 = aabb[0], A1 = aabb[1], A2 = aabb[2];
      float B0 = aabb[3], B1 = aabb[4], B2 = aabb[5];
      float v0 = fabsf(d0) < 1e-6f ? 1e-6f : d0;
      float v1 = fabsf(d1) < 1e-6f ? 1e-6f : d1;
      float v2 = fabsf(d2) < 1e-6f ? 1e-6f : d2;
      float ra0 = (B0 - o0) / v0, rb0 = (A0 - o0) / v0;
      float ra1 = (B1 - o1) / v1, rb1 = (A1 - o1) / v1;
      float ra2 = (B2 - o2) / v2, rb2 = (A2 - o2) / v2;
      float tmin = fmaxf(fmaxf(fminf(ra0, rb0), fminf(ra1, rb1)), fminf(ra2, rb2));
      tmin = fmaxf(tmin, 0.05f);
      float tmax = fminf(fminf(fmaxf(ra0, rb0), fmaxf(ra1, rb1)), fmaxf(ra2, rb2));
      tmax = fmaxf(tmax, tmin + 0.001f);
      float dt = (tmax - tmin) * (1.0f / 255.0f);
      float s0 = 2.0f / (B0 - A0), s1 = 2.0f / (B1 - A1), s2 = 2.0f / (B2 - A2);
      float4 a2, b2;
      a2.x = (o0 - A0) * s0 - 1.0f; a2.y = (o1 - A1) * s1 - 1.0f;
      a2.z = (o2 - A2) * s2 - 1.0f; a2.w = tmin;
      b2.x = d0 * s0; b2.y = d1 * s1; b2.z = d2 * s2; b2.w = dt;
      rd[r * 2] = a2;
      rd[r * 2 + 1] = b2;
    }
  }
}

// ---------------------------------------------------------------------------
// density mode (fp8 plane, fp16 line): lane sub owns 8 channels. 8B loads.
// ---------------------------------------------------------------------------
__device__ __forceinline__ float density_f8(const unsigned char* __restrict__ pl,
                                            const __half* __restrict__ ln,
                                            int x0, int y0, int l0,
                                            __half2 W00, __half2 W01,
                                            __half2 W10, __half2 W11,
                                            __half2 wl, int sub, float acc) {
  const unsigned char* p = pl + (size_t)((y0 * 256 + x0) << 4) + sub * 8;
  uint2 q00 = *(const uint2*)p;
  uint2 q01 = *(const uint2*)(p + 16);
  uint2 q10 = *(const uint2*)(p + 4096);
  uint2 q11 = *(const uint2*)(p + 4096 + 16);
  __half2 A[4], B[4], C[4], D[4], la[4], lb[4];
  dec8f8(q00, A); dec8f8(q01, B); dec8f8(q10, C); dec8f8(q11, D);
  const __half* lp = ln + (l0 << 4) + sub * 8;
  ld8h(lp, la); ld8h(lp + 16, lb);
#pragma unroll
  for (int r = 0; r < 4; ++r) {
    __half2 m = __hmul2(W00, A[r]);
    m = __hfma2(W01, B[r], m);
    m = __hfma2(W10, C[r], m);
    m = __hfma2(W11, D[r], m);
    __half2 l = lerp2(la[r], lb[r], wl);
    acc = dot2acc(m, l, acc);
  }
  return acc;
}

// ---------------------------------------------------------------------------
// app mode (fp8, 32B aligned texels): lane sub owns 16 padded channels.
// One uint4 load per corner.
// ---------------------------------------------------------------------------
__device__ __forceinline__ void app_f8(const unsigned char* __restrict__ pl,
                                       const unsigned char* __restrict__ ln,
                                       const __half2* __restrict__ btR,
                                       const __half2* __restrict__ btG,
                                       const __half2* __restrict__ btB,
                                       int x0, int y0, int l0,
                                       __half2 W00, __half2 W01,
                                       __half2 W10, __half2 W11,
                                       __half2 wl, int sub,
                                       float& dr, float& dg, float& db) {
  const unsigned char* p = pl + ((size_t)(y0 * 256 + x0) << 5) + sub * 16;
  uint4 qA = *(const uint4*)p;
  uint4 qB = *(const uint4*)(p + 32);
  uint4 qC = *(const uint4*)(p + 8192);
  uint4 qD = *(const uint4*)(p + 8192 + 32);
  const unsigned char* lp = ln + (l0 << 5) + sub * 16;
  uint4 qLA = *(const uint4*)lp;
  uint4 qLB = *(const uint4*)(lp + 32);
  __half2 A[8], B[8], C[8], D[8], LA[8], LB[8];
  dec16f8(qA, A); dec16f8(qB, B); dec16f8(qC, C); dec16f8(qD, D);
  dec16f8(qLA, LA); dec16f8(qLB, LB);
#pragma unroll
  for (int r = 0; r < 8; ++r) {
    __half2 m = __hmul2(W00, A[r]);
    m = __hfma2(W01, B[r], m);
    m = __hfma2(W10, C[r], m);
    m = __hfma2(W11, D[r], m);
    __half2 l = lerp2(LA[r], LB[r], wl);
    __half2 av = __hmul2(m, l);
    dr = dot2acc(av, btR[r], dr);
    dg = dot2acc(av, btG[r], dg);
    db = dot2acc(av, btB[r], db);
  }
}

// ---------------------------------------------------------------------------
// Fused render: block = 512 threads = 1 ray (256 samples x 2 lanes).
// Sample phase -> 4KB LDS (fp32) -> one barrier -> wave 0 scans+writes.
// NOTE: __launch_bounds__(512) with NO min-waves arg. r10 used (512,8) which
// capped VGPR at 64 -> allocator hit 32 -> 245 MB of scratch spill traffic
// (WRITE_SIZE counter) and a 1.4x regression. Let the allocator pick (~56).
// ---------------------------------------------------------------------------
__global__ __launch_bounds__(512) void render_fused(
    const float4* __restrict__ rd, const float* __restrict__ basis,
    const unsigned char* __restrict__ dpt, const __half* __restrict__ dlt,
    const unsigned char* __restrict__ apt, const unsigned char* __restrict__ alt,
    float* __restrict__ out) {
  __shared__ __align__(16) __half bth[3][3][32];  // [k][mode][ch], pad zeroed
  __shared__ __align__(16) float4 sm[NSAMP];      // alpha, r, g, b
  int tid = threadIdx.x;
  if (tid < 288) {  // 288 <= 512: single pass
    int k = tid / 96, rem = tid - k * 96;
    int m = rem >> 5, c = rem & 31;
    float v = (c < 24) ? basis[(m * 24 + c) * 3 + k] : 0.0f;
    bth[k][m][c] = __float2half(v);
  }

  int ray = blockIdx.x;
  int j = tid >> 1, sub = tid & 1;

  float4 ra = rd[ray * 2];
  float4 rb = rd[ray * 2 + 1];
  float z = fmaf((float)j, rb.w, ra.w);
  float c0 = fmaf(rb.x, z, ra.x);
  float c1 = fmaf(rb.y, z, ra.y);
  float c2 = fmaf(rb.z, z, ra.z);
  bool inside = (fabsf(c0) <= 1.0f) && (fabsf(c1) <= 1.0f) && (fabsf(c2) <= 1.0f);

  __syncthreads();  // bth ready

  float sig = 0.f, dr = 0.f, dg = 0.f, db = 0.f;
  if (inside) {
    int i0, i1, i2;
    float w0, w1, w2;
    grid_uv(c0, i0, w0);
    grid_uv(c1, i1, w1);
    grid_uv(c2, i2, w2);
    __half2 h0 = __float2half2_rn(w0);
    __half2 h1 = __float2half2_rn(w1);
    __half2 h2 = __float2half2_rn(w2);
    // MAT_MODE = [(0,1),(0,2),(1,2)], VEC_MODE = [2,1,0]
    __half2 Wa00, Wa01, Wa10, Wa11;  // mode 0: (w0,w1)
    __half2 Wb00, Wb01, Wb10, Wb11;  // mode 1: (w0,w2)
    __half2 Wc00, Wc01, Wc10, Wc11;  // mode 2: (w1,w2)
    bilin_w(w0, w1, Wa00, Wa01, Wa10, Wa11);
    bilin_w(w0, w2, Wb00, Wb01, Wb10, Wb11);
    bilin_w(w1, w2, Wc00, Wc01, Wc10, Wc11);

    sig = density_f8(dpt + 0 * 1048576, dlt + 0 * 4096, i0, i1, i2,
                     Wa00, Wa01, Wa10, Wa11, h2, sub, sig);
    sig = density_f8(dpt + 1 * 1048576, dlt + 1 * 4096, i0, i2, i1,
                     Wb00, Wb01, Wb10, Wb11, h1, sub, sig);
    sig = density_f8(dpt + 2 * 1048576, dlt + 2 * 4096, i1, i2, i0,
                     Wc00, Wc01, Wc10, Wc11, h0, sub, sig);
    app_f8(apt + 0 * 2097152, alt + 0 * 8192,
           (const __half2*)&bth[0][0][sub * 16], (const __half2*)&bth[1][0][sub * 16],
           (const __half2*)&bth[2][0][sub * 16], i0, i1, i2,
           Wa00, Wa01, Wa10, Wa11, h2, sub, dr, dg, db);
    app_f8(apt + 1 * 2097152, alt + 1 * 8192,
           (const __half2*)&bth[0][1][sub * 16], (const __half2*)&bth[1][1][sub * 16],
           (const __half2*)&bth[2][1][sub * 16], i0, i2, i1,
           Wb00, Wb01, Wb10, Wb11, h1, sub, dr, dg, db);
    app_f8(apt + 2 * 2097152, alt + 2 * 8192,
           (const __half2*)&bth[0][2][sub * 16], (const __half2*)&bth[1][2][sub * 16],
           (const __half2*)&bth[2][2][sub * 16], i1, i2, i0,
           Wc00, Wc01, Wc10, Wc11, h0, sub, dr, dg, db);
  }
  // reduce over the 2-lane group
  sig += __shfl_xor(sig, 1, 64);
  dr += __shfl_xor(dr, 1, 64);
  dg += __shfl_xor(dg, 1, 64);
  db += __shfl_xor(db, 1, 64);

  if (sub == 0) {
    // softplus via fast log/exp: sp = max(x,0) + log(1 + exp(-|x|))
    float e = __expf(-fabsf(sig));
    float sp = fmaxf(sig, 0.f) + __logf(1.0f + e);
    float4 sv;
    sv.x = inside ? (1.0f - __expf(-sp * rb.w)) : 0.0f;
    sv.y = __builtin_amdgcn_rcpf(1.0f + __expf(-dr));
    sv.z = __builtin_amdgcn_rcpf(1.0f + __expf(-dg));
    sv.w = __builtin_amdgcn_rcpf(1.0f + __expf(-db));
    sm[j] = sv;
  }
  __syncthreads();

  // wave 0: transmittance scan + composite
  if (tid < 64) {
    int lane = tid;
    float tmin = ra.w, dt = rb.w;
    float C = 1.0f;
    float racc = 0.f, gacc = 0.f, bacc = 0.f, wsum = 0.f, dsum = 0.f;
    for (int q = 0; q < 4; ++q) {
      int jj = q * 64 + lane;
      float4 sv = sm[jj];
      float alpha = sv.x;
      float zz = fmaf((float)jj, dt, tmin);
      float p = 1.0f - alpha + 1e-10f;
#pragma unroll
      for (int off = 1; off < 64; off <<= 1) {
        float t = __shfl_up(p, off, 64);
        if (lane >= off) p *= t;
      }
      float tot = __shfl(p, 63, 64);
      float e = __shfl_up(p, 1, 64);
      if (lane == 0) e = 1.0f;
      float Tj = C * e;
      float w = alpha * Tj;
      racc += w * sv.y;
      gacc += w * sv.z;
      bacc += w * sv.w;
      wsum += w;
      dsum += w * zz;
      C *= tot;
    }
#pragma unroll
    for (int off = 32; off > 0; off >>= 1) {
      racc += __shfl_down(racc, off, 64);
      gacc += __shfl_down(gacc, off, 64);
      bacc += __shfl_down(bacc, off, 64);
      wsum += __shfl_down(wsum, off, 64);
      dsum += __shfl_down(dsum, off, 64);
    }
    if (lane == 0) {
      float bgw = 1.0f - wsum;  // WHITE_BG
      out[ray * 3 + 0] = fminf(fmaxf(racc + bgw, 0.f), 1.f);
      out[ray * 3 + 1] = fminf(fmaxf(gacc + bgw, 0.f), 1.f);
      out[ray * 3 + 2] = fminf(fmaxf(bacc + bgw, 0.f), 1.f);
      out[NRAYS * 3 + ray] = dsum;
    }
  }
}

// ---------------------------------------------------------------------------
// Fallback (ws too small): single-kernel fp32 render on original layout.
// ---------------------------------------------------------------------------
__device__ __forceinline__ float density_orig(const float* __restrict__ plane,
                                              const float* __restrict__ line,
                                              float cx, float cy, float cw) {
  int x0, y0, l0; float wx, wy, wl;
  grid_uv(cx, x0, wx); grid_uv(cy, y0, wy); grid_uv(cw, l0, wl);
  int base = y0 * 256 + x0;
  float s = 0.0f;
#pragma unroll 4
  for (int c = 0; c < 16; ++c) {
    const float* pc = plane + c * 65536;
    float v00 = pc[base], v01 = pc[base + 1];
    float v10 = pc[base + 256], v11 = pc[base + 257];
    float top = fmaf(wx, v01 - v00, v00);
    float bot = fmaf(wx, v11 - v10, v10);
    float mid = fmaf(wy, bot - top, top);
    float la = line[c * 256 + l0], lb = line[c * 256 + l0 + 1];
    float lv = fmaf(wl, lb - la, la);
    s += mid * lv;
  }
  return s;
}

__device__ __forceinline__ void app_orig(const float* __restrict__ plane,
                                         const float* __restrict__ line,
                                         const float* __restrict__ btR,
                                         const float* __restrict__ btG,
                                         const float* __restrict__ btB,
                                         float cx, float cy, float cw,
                                         float& dr, float& dg, float& db) {
  int x0, y0, l0; float wx, wy, wl;
  grid_uv(cx, x0, wx); grid_uv(cy, y0, wy); grid_uv(cw, l0, wl);
  int base = y0 * 256 + x0;
#pragma unroll 4
  for (int c = 0; c < 24; ++c) {
    const float* pc = plane + c * 65536;
    float v00 = pc[base], v01 = pc[base + 1];
    float v10 = pc[base + 256], v11 = pc[base + 257];
    float top = fmaf(wx, v01 - v00, v00);
    float bot = fmaf(wx, v11 - v10, v10);
    float mid = fmaf(wy, bot - top, top);
    float la = line[c * 256 + l0], lb = line[c * 256 + l0 + 1];
    float lv = fmaf(wl, lb - la, la);
    float av = mid * lv;
    dr += av * btR[c]; dg += av * btG[c]; db += av * btB[c];
  }
}

__global__ __launch_bounds__(256) void render_fallback(
    const float* __restrict__ rays, const float* __restrict__ basis,
    const float* __restrict__ aabb, const float* __restrict__ dplane,
    const float* __restrict__ dline, const float* __restrict__ aplane,
    const float* __restrict__ aline, float* __restrict__ out) {
  __shared__ float bt[3 * 72];
  int tid = threadIdx.x;
  if (tid < 216) {
    int k = tid / 72, r = tid - k * 72;
    bt[tid] = basis[r * 3 + k];
  }
  __syncthreads();
  int lane = tid & 63;
  int ray = blockIdx.x * 4 + (tid >> 6);

  float o0 = rays[ray * 6 + 0], o1 = rays[ray * 6 + 1], o2 = rays[ray * 6 + 2];
  float d0 = rays[ray * 6 + 3], d1 = rays[ray * 6 + 4], d2 = rays[ray * 6 + 5];
  float A0 = aabb[0], A1 = aabb[1], A2 = aabb[2];
  float B0 = aabb[3], B1 = aabb[4], B2 = aabb[5];
  float v0 = fabsf(d0) < 1e-6f ? 1e-6f : d0;
  float v1 = fabsf(d1) < 1e-6f ? 1e-6f : d1;
  float v2 = fabsf(d2) < 1e-6f ? 1e-6f : d2;
  float ra0 = (B0 - o0) / v0, rb0 = (A0 - o0) / v0;
  float ra1 = (B1 - o1) / v1, rb1 = (A1 - o1) / v1;
  float ra2 = (B2 - o2) / v2, rb2 = (A2 - o2) / v2;
  float tmin = fmaxf(fmaxf(fminf(ra0, rb0), fminf(ra1, rb1)), fminf(ra2, rb2));
  tmin = fmaxf(tmin, 0.05f);
  float tmax = fminf(fminf(fmaxf(ra0, rb0), fmaxf(ra1, rb1)), fmaxf(ra2, rb2));
  tmax = fmaxf(tmax, tmin + 0.001f);
  float dt = (tmax - tmin) * (1.0f / 255.0f);
  float s0 = 2.0f / (B0 - A0), s1 = 2.0f / (B1 - A1), s2 = 2.0f / (B2 - A2);

  float C = 1.0f;
  float racc = 0.f, gacc = 0.f, bacc = 0.f, wsum = 0.f, dsum = 0.f;
  for (int q = 0; q < 4; ++q) {
    int j = q * 64 + lane;
    float sfrac = (float)j * (1.0f / 255.0f);
    float z = tmin * (1.0f - sfrac) + tmax * sfrac;
    float c0 = (o0 + d0 * z - A0) * s0 - 1.0f;
    float c1 = (o1 + d1 * z - A1) * s1 - 1.0f;
    float c2 = (o2 + d2 * z - A2) * s2 - 1.0f;
    bool inside = (fabsf(c0) <= 1.0f) && (fabsf(c1) <= 1.0f) && (fabsf(c2) <= 1.0f);
    float alpha = 0.f, cr = 0.f, cg = 0.f, cb = 0.f;
    if (inside) {
      float sig = 0.f, dr = 0.f, dg = 0.f, db = 0.f;
      sig += density_orig(dplane + 0 * 1048576, dline + 0 * 4096, c0, c1, c2);
      sig += density_orig(dplane + 1 * 1048576, dline + 1 * 4096, c0, c2, c1);
      sig += density_orig(dplane + 2 * 1048576, dline + 2 * 4096, c1, c2, c0);
      app_orig(aplane + 0 * 1572864, aline + 0 * 6144,
               &bt[0 * 72 + 0], &bt[1 * 72 + 0], &bt[2 * 72 + 0],
               c0, c1, c2, dr, dg, db);
      app_orig(aplane + 1 * 1572864, aline + 1 * 6144,
               &bt[0 * 72 + 24], &bt[1 * 72 + 24], &bt[2 * 72 + 24],
               c0, c2, c1, dr, dg, db);
      app_orig(aplane + 2 * 1572864, aline + 2 * 6144,
               &bt[0 * 72 + 48], &bt[1 * 72 + 48], &bt[2 * 72 + 48],
               c1, c2, c0, dr, dg, db);
      float sp = fmaxf(sig, 0.f) + log1pf(expf(-fabsf(sig)));
      alpha = 1.0f - expf(-sp * dt);
      cr = 1.0f / (1.0f + expf(-dr));
      cg = 1.0f / (1.0f + expf(-dg));
      cb = 1.0f / (1.0f + expf(-db));
    }
    float p = 1.0f - alpha + 1e-10f;
#pragma unroll
    for (int off = 1; off < 64; off <<= 1) {
      float t = __shfl_up(p, off, 64);
      if (lane >= off) p *= t;
    }
    float tot = __shfl(p, 63, 64);
    float e = __shfl_up(p, 1, 64);
    if (lane == 0) e = 1.0f;
    float Tj = C * e;
    float w = alpha * Tj;
    racc += w * cr; gacc += w * cg; bacc += w * cb;
    wsum += w; dsum += w * z;
    C *= tot;
  }
#pragma unroll
  for (int off = 32; off > 0; off >>= 1) {
    racc += __shfl_down(racc, off, 64);
    gacc += __shfl_down(gacc, off, 64);
    bacc += __shfl_down(bacc, off, 64);
    wsum += __shfl_down(wsum, off, 64);
    dsum += __shfl_down(dsum, off, 64);
  }
  if (lane == 0) {
    float bgw = 1.0f - wsum;
    out[ray * 3 + 0] = fminf(fmaxf(racc + bgw, 0.f), 1.f);
    out[ray * 3 + 1] = fminf(fmaxf(gacc + bgw, 0.f), 1.f);
    out[ray * 3 + 2] = fminf(fmaxf(bacc + bgw, 0.f), 1.f);
    out[NRAYS * 3 + ray] = dsum;
  }
}

extern "C" void kernel_launch(void* const* d_in, const int* in_sizes, int n_in,
                              void* d_out, int out_size, void* d_ws, size_t ws_size,
                              hipStream_t stream) {
  const float* rays  = (const float*)d_in[0];
  const float* dp    = (const float*)d_in[1];
  const float* dl    = (const float*)d_in[2];
  const float* ap    = (const float*)d_in[3];
  const float* al    = (const float*)d_in[4];
  const float* basis = (const float*)d_in[5];
  const float* aabb  = (const float*)d_in[6];
  float* out = (float*)d_out;

  if (ws_size >= WS_NEED) {
    char* ws = (char*)d_ws;
    unsigned char* dpt = (unsigned char*)(ws + DPT_B);
    __half* dlt = (__half*)(ws + DLT_B);
    unsigned char* apt = (unsigned char*)(ws + APT_B);
    unsigned char* alt = (unsigned char*)(ws + ALT_B);
    float4* rayd = (float4*)(ws + RAY_B);
    prep_kernel<<<1558, 256, 0, stream>>>(dp, ap, dl, al, rays, aabb,
                                          dpt, apt, dlt, alt, rayd);
    render_fused<<<NRAYS, 512, 0, stream>>>(rayd, basis, dpt, dlt, apt, alt, out);
  } else {
    render_fallback<<<NRAYS / 4, 256, 0, stream>>>(
        rays, basis, aabb, dp, dl, ap, al, out);
  }
}